// Round 1
// 227.127 us; speedup vs baseline: 1.0176x; 1.0176x over previous
//
#include <hip/hip_runtime.h>

// Fused: h = relu(X @ M + d), s0 = sum(h), where
//   M = W^T @ RW (20x20), d = b @ RW + 1 (20,)  -- precomputed by setup_kernel.
// Then n = #halvings of f32(s0) until <= 1; out = f32(s0) * 2^-n.
//
// Round-6 changes vs round-5 (231.1 us):
//  (1) Coalesced staging: each wave loads CONTIGUOUS 1KB chunks of X
//      (lane i -> float4 #i) instead of per-lane 160B-strided rows, and
//      redistributes through LDS. LDS layout is padded to an 11-float4
//      per-thread pitch (slot + slot/10): read base slot = 11*tid, 11 odd
//      => every 8 consecutive lanes hit all 8 bank-quads => conflict-free
//      ds_read_b128 at the data-path floor. Kills the ~160-cacheline/instr
//      TA serialization of the old per-lane-row pattern.
//  (2) finalize_kernel merged into fused_mlp_sum via last-block-done ticket
//      (counter in ws, zeroed by setup_kernel each replay). Cross-XCD
//      correctness: release-store partials, acq_rel ticket, agent-scope
//      atomic loads in the reader (per-XCD L2s are not coherent; a plain
//      read could hit a stale line containing neighbors' partials).
//  Control flow stays UNIFORM and branch-free through the load/FMA body so
//  Mt/dvec remain scalarized (s_load, SGPR operands, scalar pipe).

#define D 20
#define BLOCK 256
#define RPT 2
#define RPB (BLOCK * RPT)           // 512 rows per block
#define F4PB (RPB * D / 4)          // 2560 float4 per block chunk
#define NLD (F4PB / BLOCK)          // 10 float4 loads per thread
#define LDS_F4 (F4PB + F4PB / 10)   // 2816 padded float4 slots (45,056 B)
#define WS_PARTIALS_BYTES 32768

// d_ws layout:
//   [0, 32768)            : double partials[4096] (one per block; 3907 used)
//   [32768, +1600)        : float Mt[400], Mt[j*D+k] = M[k][j]
//   [+1600, +1680)        : float dvec[20]
//   [+1680, +1684)        : unsigned counter (last-block ticket)

__global__ void setup_kernel(const float* __restrict__ W,
                             const float* __restrict__ b,
                             const float* __restrict__ RW,
                             float* __restrict__ Mt,
                             float* __restrict__ dvec,
                             unsigned* __restrict__ counter) {
    const int tid = threadIdx.x;
    if (tid == 0) *counter = 0u;  // ws is re-poisoned each iteration
    for (int idx = tid; idx < D * D; idx += blockDim.x) {
        const int j = idx / D, k = idx % D;
        float s = 0.0f;
        for (int i = 0; i < D; ++i)
            s = fmaf(W[i * D + k], RW[i * D + j], s);
        Mt[idx] = s;  // idx == j*D + k
    }
    if (tid < D) {
        float s = 1.0f;
        for (int i = 0; i < D; ++i)
            s = fmaf(b[i], RW[i * D + tid], s);
        dvec[tid] = s;
    }
}

__global__ void __launch_bounds__(BLOCK)
fused_mlp_sum(const float* __restrict__ X,
              const float* __restrict__ Mt,
              const float* __restrict__ dvec,
              double* __restrict__ partials,
              unsigned* __restrict__ counter,
              float* __restrict__ out,
              int nrows) {
    __shared__ float4 lds4[LDS_F4];
    __shared__ float wave_sums[BLOCK / 64];
    __shared__ double dsum[BLOCK / 64];
    __shared__ int is_last;

    const int tid = threadIdx.x;
    const int bid = blockIdx.x;

    // ---- Stage 1: fully-coalesced global -> LDS (padded layout) ----
    const long long total_f4 = ((long long)nrows * D) >> 2;
    const long long base_f4 = (long long)bid * F4PB;
    const long long rem = total_f4 - base_f4;
    const int chunk_f4 = (rem < (long long)F4PB) ? (int)rem : F4PB;
    const float4* __restrict__ xg = (const float4*)X + base_f4;

#pragma unroll
    for (int q = 0; q < NLD; ++q) {
        const int s = tid + BLOCK * q;              // linear float4 slot
        const int sc = (s < chunk_f4) ? s : (chunk_f4 - 1);  // in-bounds clamp
        lds4[s + s / 10] = xg[sc];                  // 11-slot/thread pitch
    }
    __syncthreads();

    // ---- Stage 2: LDS -> regs (conflict-free: base slot 11*tid, 11 odd) ----
    float x0[D], x1[D];
    const int b4 = 11 * tid;
#pragma unroll
    for (int q = 0; q < 5; ++q) {
        const float4 v = lds4[b4 + q];
        x0[4 * q + 0] = v.x; x0[4 * q + 1] = v.y;
        x0[4 * q + 2] = v.z; x0[4 * q + 3] = v.w;
        const float4 u = lds4[b4 + 5 + q];
        x1[4 * q + 0] = u.x; x1[4 * q + 1] = u.y;
        x1[4 * q + 2] = u.z; x1[4 * q + 3] = u.w;
    }

    // ---- Stage 3: 2x (20x20) FMA with s_load'ed Mt/dvec (uniform CF) ----
    float lsum = 0.0f;
#pragma unroll
    for (int j = 0; j < D; ++j) {
        float t0 = dvec[j];   // uniform addr + uniform CF -> s_load (SGPR)
        float t1 = t0;
#pragma unroll
        for (int k = 0; k < D; ++k) {
            const float m = Mt[j * D + k];  // s_load, scalar pipe
            t0 = fmaf(x0[k], m, t0);
            t1 = fmaf(x1[k], m, t1);
        }
        lsum += fmaxf(t0, 0.0f) + fmaxf(t1, 0.0f);
    }
    // nrows is even and RPB divides the per-thread row pair, so one flag
    // covers both rows.
    const bool valid = (long long)bid * RPB + 2 * tid < (long long)nrows;
    lsum = valid ? lsum : 0.0f;

    // ---- Block reduction -> one partial per block ----
#pragma unroll
    for (int off = 32; off > 0; off >>= 1)
        lsum += __shfl_down(lsum, off, 64);
    if ((tid & 63) == 0) wave_sums[tid >> 6] = lsum;
    __syncthreads();

    if (tid == 0) {
        float bs = wave_sums[0] + wave_sums[1] + wave_sums[2] + wave_sums[3];
        // Release store: must be visible to the last block on another XCD.
        __hip_atomic_store(&partials[bid], (double)bs, __ATOMIC_RELEASE,
                           __HIP_MEMORY_SCOPE_AGENT);
        const unsigned t = __hip_atomic_fetch_add(counter, 1u, __ATOMIC_ACQ_REL,
                                                  __HIP_MEMORY_SCOPE_AGENT);
        is_last = (t == gridDim.x - 1);
    }
    __syncthreads();

    // ---- Last block finalizes (replaces finalize_kernel launch) ----
    if (is_last) {
        double s = 0.0;
        for (int i = tid; i < (int)gridDim.x; i += BLOCK)
            s += __hip_atomic_load(&partials[i], __ATOMIC_RELAXED,
                                   __HIP_MEMORY_SCOPE_AGENT);
#pragma unroll
        for (int off = 32; off > 0; off >>= 1)
            s += __shfl_down(s, off, 64);
        if ((tid & 63) == 0) dsum[tid >> 6] = s;
        __syncthreads();
        if (tid == 0) {
            const double s0 = dsum[0] + dsum[1] + dsum[2] + dsum[3];
            float f = (float)s0;   // reference's s0 is f32
            while (f > 1.0f) f *= 0.5f;  // exact power-of-2 halvings
            out[0] = f;
        }
    }
}

extern "C" void kernel_launch(void* const* d_in, const int* in_sizes, int n_in,
                              void* d_out, int out_size, void* d_ws, size_t ws_size,
                              hipStream_t stream) {
    const float* X  = (const float*)d_in[0];
    const float* W  = (const float*)d_in[1];
    const float* b  = (const float*)d_in[2];
    const float* RW = (const float*)d_in[3];
    float* out = (float*)d_out;

    double* partials = (double*)d_ws;
    float*  Mt = (float*)((char*)d_ws + WS_PARTIALS_BYTES);
    float*  dv = Mt + D * D;
    unsigned* counter = (unsigned*)((char*)d_ws + WS_PARTIALS_BYTES + 1600 + 80);

    const int nrows = in_sizes[0] / (D * 4);  // 2,000,000

    setup_kernel<<<1, 256, 0, stream>>>(W, b, RW, Mt, dv, counter);

    const int blocks = (nrows + RPB - 1) / RPB;  // 3907
    fused_mlp_sum<<<blocks, BLOCK, 0, stream>>>(X, Mt, dv, partials, counter,
                                                out, nrows);
}